// Round 2
// baseline (808.130 us; speedup 1.0000x reference)
//
#include <hip/hip_runtime.h>

#define U_DIM 400
#define V_DIM 400
#define TEXELS (U_DIM * V_DIM)
#define JSHIFT 3                       // bin = (m, i1, j1>>3)
#define JBINS ((V_DIM + (1 << JSHIFT) - 1) >> JSHIFT)   // 50

struct __attribute__((aligned(8))) Rec {
  float x0, x1, x2, iu, jv;
  unsigned meta;                       // idx | (m << 30)
};

__device__ __forceinline__ void uv_to_coords(float uu, float vv,
                                             float& iu, float& jv) {
  iu = uu * (float)U_DIM; if (iu >= (float)U_DIM) iu = (float)(U_DIM - 1);
  jv = vv * (float)V_DIM; if (jv >= (float)V_DIM) jv = (float)(V_DIM - 1);
}

// ---------------- pipeline kernels ----------------

__global__ __launch_bounds__(256) void zero_kernel(unsigned* __restrict__ p, int n) {
  int i = blockIdx.x * blockDim.x + threadIdx.x;
  if (i < n) p[i] = 0u;
}

// [M,U*V,9]+[M,U*V,3] -> 16-float 64B records: [0:9)=W, [9:12)=b, [12:16)=0
__global__ __launch_bounds__(256) void repack_kernel(
    const float* __restrict__ mp, const float* __restrict__ bp,
    float* __restrict__ packed, int total_dwords) {
  int idx = blockIdx.x * blockDim.x + threadIdx.x;
  if (idx >= total_dwords) return;
  int t = idx >> 4;
  int k = idx & 15;
  float val = 0.0f;
  if (k < 9)       val = mp[t * 9 + k];
  else if (k < 12) val = bp[t * 3 + (k - 9)];
  packed[idx] = val;
}

__global__ __launch_bounds__(256) void hist_kernel(
    const int* __restrict__ m, const float* __restrict__ u,
    const float* __restrict__ v, unsigned* __restrict__ hist, int N) {
  int n = blockIdx.x * blockDim.x + threadIdx.x;
  if (n >= N) return;
  float iu, jv;
  uv_to_coords(u[n], v[n], iu, jv);
  int i1 = (int)floorf(iu);
  int j1 = (int)floorf(jv);
  int key = (m[n] * U_DIM + i1) * JBINS + (j1 >> JSHIFT);
  atomicAdd(&hist[key], 1u);
}

#define SCAN_THREADS 1024
// single-workgroup exclusive scan: cursor[i] = sum(hist[0..i))
__global__ __launch_bounds__(SCAN_THREADS) void scan_kernel(
    const unsigned* __restrict__ hist, unsigned* __restrict__ cursor, int nb) {
  __shared__ unsigned buf[2][SCAN_THREADS];
  __shared__ unsigned carry_s;
  if (threadIdx.x == 0) carry_s = 0u;
  __syncthreads();
  for (int base = 0; base < nb; base += SCAN_THREADS) {
    int i = base + threadIdx.x;
    unsigned vv = (i < nb) ? hist[i] : 0u;
    int src = 0;
    buf[0][threadIdx.x] = vv;
    __syncthreads();
    for (int off = 1; off < SCAN_THREADS; off <<= 1) {
      unsigned t = buf[src][threadIdx.x];
      if ((int)threadIdx.x >= off) t += buf[src][threadIdx.x - off];
      buf[1 - src][threadIdx.x] = t;
      src = 1 - src;
      __syncthreads();
    }
    unsigned incl = buf[src][threadIdx.x];
    unsigned excl = incl - vv + carry_s;
    if (i < nb) cursor[i] = excl;
    __syncthreads();                         // everyone read carry_s
    if (threadIdx.x == SCAN_THREADS - 1) carry_s += incl;
    __syncthreads();
  }
}

__global__ __launch_bounds__(256) void scatter_kernel(
    const float* __restrict__ x, const int* __restrict__ m,
    const float* __restrict__ u, const float* __restrict__ v,
    unsigned* __restrict__ cursor, Rec* __restrict__ sorted, int N) {
  int n = blockIdx.x * blockDim.x + threadIdx.x;
  if (n >= N) return;
  float iu, jv;
  uv_to_coords(u[n], v[n], iu, jv);
  int i1 = (int)floorf(iu);
  int j1 = (int)floorf(jv);
  int mm = m[n];
  int key = (mm * U_DIM + i1) * JBINS + (j1 >> JSHIFT);
  unsigned slot = atomicAdd(&cursor[key], 1u);
  Rec r;
  r.x0 = x[3 * n + 0];
  r.x1 = x[3 * n + 1];
  r.x2 = x[3 * n + 2];
  r.iu = iu;
  r.jv = jv;
  r.meta = (unsigned)n | ((unsigned)mm << 30);
  sorted[slot] = r;
}

__device__ __forceinline__ void corner_setup(float iu, float jv,
                                             float* w, int* t) {
  float i1f = floorf(iu), j1f = floorf(jv);
  int i1 = (int)i1f, j1 = (int)j1f;
  int i2 = i1 + 1; if (i2 == U_DIM) i2 = 0;
  int j2 = j1 + 1; if (j2 == V_DIM) j2 = 0;
  float ir = iu - i1f, jr = jv - j1f;
  w[0] = (1.0f - ir) * (1.0f - jr);
  w[1] = ir * (1.0f - jr);
  w[2] = (1.0f - ir) * jr;
  w[3] = ir * jr;
  t[0] = i1 * V_DIM + j1;
  t[1] = i2 * V_DIM + j1;
  t[2] = i1 * V_DIM + j2;
  t[3] = i2 * V_DIM + j2;
}

__device__ __forceinline__ void finish_point(const float* acc, float x0, float x1,
                                             float x2, float* __restrict__ out,
                                             unsigned idx) {
  float o0 = fmaf(x0, acc[0], fmaf(x1, acc[3], fmaf(x2, acc[6], acc[9])));
  float o1 = fmaf(x0, acc[1], fmaf(x1, acc[4], fmaf(x2, acc[7], acc[10])));
  float o2 = fmaf(x0, acc[2], fmaf(x1, acc[5], fmaf(x2, acc[8], acc[11])));
  out[3 * idx + 0] = o0;
  out[3 * idx + 1] = o1;
  out[3 * idx + 2] = o2;
}

__global__ __launch_bounds__(256) void gather_packed_kernel(
    const Rec* __restrict__ sorted, const float4* __restrict__ packed,
    float* __restrict__ out, int N) {
  int n = blockIdx.x * blockDim.x + threadIdx.x;
  if (n >= N) return;
  Rec r = sorted[n];
  float w[4]; int t[4];
  corner_setup(r.iu, r.jv, w, t);
  const float4* base = packed + (size_t)(r.meta >> 30) * ((size_t)TEXELS * 4);
  float acc[12];
#pragma unroll
  for (int c = 0; c < 12; ++c) acc[c] = 0.0f;
#pragma unroll
  for (int c = 0; c < 4; ++c) {
    const float4* p = base + (size_t)t[c] * 4;
    float4 q0 = p[0];
    float4 q1 = p[1];
    float4 q2 = p[2];
    float wc = w[c];
    acc[0]  = fmaf(wc, q0.x, acc[0]);
    acc[1]  = fmaf(wc, q0.y, acc[1]);
    acc[2]  = fmaf(wc, q0.z, acc[2]);
    acc[3]  = fmaf(wc, q0.w, acc[3]);
    acc[4]  = fmaf(wc, q1.x, acc[4]);
    acc[5]  = fmaf(wc, q1.y, acc[5]);
    acc[6]  = fmaf(wc, q1.z, acc[6]);
    acc[7]  = fmaf(wc, q1.w, acc[7]);
    acc[8]  = fmaf(wc, q2.x, acc[8]);
    acc[9]  = fmaf(wc, q2.y, acc[9]);
    acc[10] = fmaf(wc, q2.z, acc[10]);
    acc[11] = fmaf(wc, q2.w, acc[11]);
  }
  finish_point(acc, r.x0, r.x1, r.x2, out, r.meta & 0x3FFFFFFFu);
}

// variant gathering straight from the original (unpacked) tables
__global__ __launch_bounds__(256) void gather_direct_kernel(
    const Rec* __restrict__ sorted, const float* __restrict__ mp,
    const float* __restrict__ bp, float* __restrict__ out, int N) {
  int n = blockIdx.x * blockDim.x + threadIdx.x;
  if (n >= N) return;
  Rec r = sorted[n];
  float w[4]; int t[4];
  corner_setup(r.iu, r.jv, w, t);
  size_t mb = (size_t)(r.meta >> 30) * TEXELS;
  float acc[12];
#pragma unroll
  for (int c = 0; c < 12; ++c) acc[c] = 0.0f;
#pragma unroll
  for (int c = 0; c < 4; ++c) {
    const float* pm = mp + (mb + t[c]) * 9;
    const float* pb = bp + (mb + t[c]) * 3;
    float wc = w[c];
#pragma unroll
    for (int k = 0; k < 9; ++k) acc[k] = fmaf(wc, pm[k], acc[k]);
#pragma unroll
    for (int k = 0; k < 3; ++k) acc[9 + k] = fmaf(wc, pb[k], acc[9 + k]);
  }
  finish_point(acc, r.x0, r.x1, r.x2, out, r.meta & 0x3FFFFFFFu);
}

// ---------------- round-1 fallback kernels (no/low workspace) ----------------

__global__ __launch_bounds__(256) void interp_packed_kernel(
    const float* __restrict__ x, const int* __restrict__ mat,
    const float* __restrict__ u, const float* __restrict__ v,
    const float4* __restrict__ packed, float* __restrict__ out, int N) {
  int n = blockIdx.x * blockDim.x + threadIdx.x;
  if (n >= N) return;
  float iu, jv;
  uv_to_coords(u[n], v[n], iu, jv);
  float w[4]; int t[4];
  corner_setup(iu, jv, w, t);
  const float4* base = packed + (size_t)mat[n] * ((size_t)TEXELS * 4);
  float acc[12];
#pragma unroll
  for (int c = 0; c < 12; ++c) acc[c] = 0.0f;
#pragma unroll
  for (int c = 0; c < 4; ++c) {
    const float4* p = base + (size_t)t[c] * 4;
    float4 q0 = p[0];
    float4 q1 = p[1];
    float4 q2 = p[2];
    float wc = w[c];
    acc[0]  = fmaf(wc, q0.x, acc[0]);
    acc[1]  = fmaf(wc, q0.y, acc[1]);
    acc[2]  = fmaf(wc, q0.z, acc[2]);
    acc[3]  = fmaf(wc, q0.w, acc[3]);
    acc[4]  = fmaf(wc, q1.x, acc[4]);
    acc[5]  = fmaf(wc, q1.y, acc[5]);
    acc[6]  = fmaf(wc, q1.z, acc[6]);
    acc[7]  = fmaf(wc, q1.w, acc[7]);
    acc[8]  = fmaf(wc, q2.x, acc[8]);
    acc[9]  = fmaf(wc, q2.y, acc[9]);
    acc[10] = fmaf(wc, q2.z, acc[10]);
    acc[11] = fmaf(wc, q2.w, acc[11]);
  }
  float x0 = x[3 * n + 0], x1 = x[3 * n + 1], x2 = x[3 * n + 2];
  finish_point(acc, x0, x1, x2, out, (unsigned)n);
}

__global__ __launch_bounds__(256) void interp_direct_kernel(
    const float* __restrict__ x, const int* __restrict__ mat,
    const float* __restrict__ u, const float* __restrict__ v,
    const float* __restrict__ mp, const float* __restrict__ bp,
    float* __restrict__ out, int N) {
  int n = blockIdx.x * blockDim.x + threadIdx.x;
  if (n >= N) return;
  float iu, jv;
  uv_to_coords(u[n], v[n], iu, jv);
  float w[4]; int t[4];
  corner_setup(iu, jv, w, t);
  size_t mb = (size_t)mat[n] * TEXELS;
  float acc[12];
#pragma unroll
  for (int c = 0; c < 12; ++c) acc[c] = 0.0f;
#pragma unroll
  for (int c = 0; c < 4; ++c) {
    const float* pm = mp + (mb + t[c]) * 9;
    const float* pb = bp + (mb + t[c]) * 3;
    float wc = w[c];
#pragma unroll
    for (int k = 0; k < 9; ++k) acc[k] = fmaf(wc, pm[k], acc[k]);
#pragma unroll
    for (int k = 0; k < 3; ++k) acc[9 + k] = fmaf(wc, pb[k], acc[9 + k]);
  }
  float x0 = x[3 * n + 0], x1 = x[3 * n + 1], x2 = x[3 * n + 2];
  finish_point(acc, x0, x1, x2, out, (unsigned)n);
}

// ---------------- launch ----------------

static inline size_t align_up(size_t v, size_t a) { return (v + a - 1) & ~(a - 1); }

extern "C" void kernel_launch(void* const* d_in, const int* in_sizes, int n_in,
                              void* d_out, int out_size, void* d_ws, size_t ws_size,
                              hipStream_t stream) {
  const float* x  = (const float*)d_in[0];
  const int*   m  = (const int*)d_in[1];
  const float* u  = (const float*)d_in[2];
  const float* v  = (const float*)d_in[3];
  const float* mp = (const float*)d_in[4];
  const float* bp = (const float*)d_in[5];
  float* out = (float*)d_out;

  int N = in_sizes[1];
  int M = in_sizes[4] / (TEXELS * 9);

  const int B = 256;
  int nblk = (N + B - 1) / B;

  size_t tbl_bytes  = (size_t)M * TEXELS * 16 * sizeof(float);
  int    nb         = M * U_DIM * JBINS;
  size_t hist_bytes = align_up((size_t)nb * sizeof(unsigned), 256);
  size_t sort_bytes = (size_t)N * sizeof(Rec);

  bool meta_ok = (M <= 4) && (N <= (1 << 30));

  size_t need_full   = align_up(tbl_bytes, 256) + 2 * hist_bytes + sort_bytes;
  size_t need_nopack = 2 * hist_bytes + sort_bytes;

  if (meta_ok && ws_size >= need_full) {
    char* base = (char*)d_ws;
    float*    packed = (float*)base;
    unsigned* hist   = (unsigned*)(base + align_up(tbl_bytes, 256));
    unsigned* cursor = (unsigned*)((char*)hist + hist_bytes);
    Rec*      sorted = (Rec*)((char*)cursor + hist_bytes);

    zero_kernel<<<(nb + B - 1) / B, B, 0, stream>>>(hist, nb);
    int total_dwords = M * TEXELS * 16;
    repack_kernel<<<(total_dwords + B - 1) / B, B, 0, stream>>>(mp, bp, packed, total_dwords);
    hist_kernel<<<nblk, B, 0, stream>>>(m, u, v, hist, N);
    scan_kernel<<<1, SCAN_THREADS, 0, stream>>>(hist, cursor, nb);
    scatter_kernel<<<nblk, B, 0, stream>>>(x, m, u, v, cursor, sorted, N);
    gather_packed_kernel<<<nblk, B, 0, stream>>>(sorted, (const float4*)packed, out, N);
  } else if (meta_ok && ws_size >= need_nopack) {
    char* base = (char*)d_ws;
    unsigned* hist   = (unsigned*)base;
    unsigned* cursor = (unsigned*)(base + hist_bytes);
    Rec*      sorted = (Rec*)(base + 2 * hist_bytes);

    zero_kernel<<<(nb + B - 1) / B, B, 0, stream>>>(hist, nb);
    hist_kernel<<<nblk, B, 0, stream>>>(m, u, v, hist, N);
    scan_kernel<<<1, SCAN_THREADS, 0, stream>>>(hist, cursor, nb);
    scatter_kernel<<<nblk, B, 0, stream>>>(x, m, u, v, cursor, sorted, N);
    gather_direct_kernel<<<nblk, B, 0, stream>>>(sorted, mp, bp, out, N);
  } else if (ws_size >= tbl_bytes) {
    int total_dwords = M * TEXELS * 16;
    repack_kernel<<<(total_dwords + B - 1) / B, B, 0, stream>>>(mp, bp, (float*)d_ws, total_dwords);
    interp_packed_kernel<<<nblk, B, 0, stream>>>(x, m, u, v, (const float4*)d_ws, out, N);
  } else {
    interp_direct_kernel<<<nblk, B, 0, stream>>>(x, m, u, v, mp, bp, out, N);
  }
}

// Round 4
// 609.129 us; speedup vs baseline: 1.3267x; 1.3267x over previous
//
#include <hip/hip_runtime.h>
#include <hip/hip_fp16.h>

#define U_DIM 400
#define V_DIM 400
#define TEXELS (U_DIM * V_DIM)
#define NKEY 4                 // sort by material only

typedef unsigned long long u64;

__device__ __forceinline__ void uv_to_coords(float uu, float vv,
                                             float& iu, float& jv) {
  iu = uu * (float)U_DIM; if (iu >= (float)U_DIM) iu = (float)(U_DIM - 1);
  jv = vv * (float)V_DIM; if (jv >= (float)V_DIM) jv = (float)(V_DIM - 1);
}

__device__ __forceinline__ void corner_setup(float iu, float jv,
                                             float* w, int* t) {
  float i1f = floorf(iu), j1f = floorf(jv);
  int i1 = (int)i1f, j1 = (int)j1f;
  int i2 = i1 + 1; if (i2 == U_DIM) i2 = 0;
  int j2 = j1 + 1; if (j2 == V_DIM) j2 = 0;
  float ir = iu - i1f, jr = jv - j1f;
  w[0] = (1.0f - ir) * (1.0f - jr);
  w[1] = ir * (1.0f - jr);
  w[2] = (1.0f - ir) * jr;
  w[3] = ir * jr;
  t[0] = i1 * V_DIM + j1;
  t[1] = i2 * V_DIM + j1;
  t[2] = i1 * V_DIM + j2;
  t[3] = i2 * V_DIM + j2;
}

// ---------------- pipeline kernels ----------------

__global__ __launch_bounds__(64) void zero8_kernel(unsigned* __restrict__ p) {
  if (threadIdx.x < 2 * NKEY) p[threadIdx.x] = 0u;
}

// fp16 repack: [M,U*V,9]+[M,U*V,3] -> 24B texel records (12 halves: 9 W + 3 b)
__global__ __launch_bounds__(256) void repack_fp16_kernel(
    const float* __restrict__ mp, const float* __restrict__ bp,
    u64* __restrict__ tbl, int total_texels) {
  int t = blockIdx.x * blockDim.x + threadIdx.x;
  if (t >= total_texels) return;
  const float* pw = mp + (size_t)t * 9;
  const float* pb = bp + (size_t)t * 3;
  union { __half h[12]; u64 q[3]; } u;
#pragma unroll
  for (int k = 0; k < 9; ++k) u.h[k] = __float2half(pw[k]);
#pragma unroll
  for (int k = 0; k < 3; ++k) u.h[9 + k] = __float2half(pb[k]);
  u64* d = tbl + (size_t)t * 3;
  d[0] = u.q[0]; d[1] = u.q[1]; d[2] = u.q[2];
}

// block-local histogram of 4 material keys -> 4 global atomics per block
__global__ __launch_bounds__(256) void hist_kernel(
    const int* __restrict__ m, unsigned* __restrict__ hist, int N) {
  __shared__ unsigned c[NKEY];
  if (threadIdx.x < NKEY) c[threadIdx.x] = 0u;
  __syncthreads();
  int n = blockIdx.x * blockDim.x + threadIdx.x;
  if (n < N) {
    int key = __builtin_nontemporal_load(&m[n]);
    atomicAdd(&c[key], 1u);
  }
  __syncthreads();
  if (threadIdx.x < NKEY && c[threadIdx.x])
    atomicAdd(&hist[threadIdx.x], c[threadIdx.x]);
}

// tiny exclusive scan of 4 values: cursor[k] = sum(hist[0..k))
__global__ __launch_bounds__(64) void scan4_kernel(
    const unsigned* __restrict__ hist, unsigned* __restrict__ cursor) {
  if (threadIdx.x == 0) {
    unsigned s = 0;
#pragma unroll
    for (int k = 0; k < NKEY; ++k) { cursor[k] = s; s += hist[k]; }
  }
}

// scatter: group 256 points by material in LDS, claim 4 contiguous global runs,
// write 24B recs {x0,x1,x2,iu,jv,idx|m<<30} fully coalesced.
__global__ __launch_bounds__(256) void scatter_kernel(
    const float* __restrict__ x, const int* __restrict__ m,
    const float* __restrict__ u, const float* __restrict__ v,
    unsigned* __restrict__ cursor, u64* __restrict__ sorted, int N) {
  __shared__ unsigned cnt[NKEY], start[NKEY], gbase[NKEY];
  __shared__ unsigned lkey[256];
  __shared__ float lrec[256 * 6];

  int tid = threadIdx.x;
  int n = blockIdx.x * blockDim.x + tid;
  bool valid = (n < N);

  unsigned key = 0;
  float rec[6];
  if (valid) {
    int mm = __builtin_nontemporal_load(&m[n]);
    float uu = __builtin_nontemporal_load(&u[n]);
    float vv = __builtin_nontemporal_load(&v[n]);
    float iu, jv;
    uv_to_coords(uu, vv, iu, jv);
    rec[0] = __builtin_nontemporal_load(&x[3 * n + 0]);
    rec[1] = __builtin_nontemporal_load(&x[3 * n + 1]);
    rec[2] = __builtin_nontemporal_load(&x[3 * n + 2]);
    rec[3] = iu;
    rec[4] = jv;
    unsigned meta = (unsigned)n | ((unsigned)mm << 30);
    rec[5] = __uint_as_float(meta);
    key = (unsigned)mm;
  }

  if (tid < NKEY) cnt[tid] = 0u;
  __syncthreads();
  unsigned rank = valid ? atomicAdd(&cnt[key], 1u) : 0u;
  __syncthreads();
  if (tid < NKEY) gbase[tid] = atomicAdd(&cursor[tid], cnt[tid]);
  if (tid == 0) {
    unsigned s = 0;
#pragma unroll
    for (int k = 0; k < NKEY; ++k) { start[k] = s; s += cnt[k]; }
  }
  __syncthreads();
  if (valid) {
    unsigned lpos = start[key] + rank;
    lkey[lpos] = key;
#pragma unroll
    for (int k = 0; k < 6; ++k) lrec[lpos * 6 + k] = rec[k];
  }
  __syncthreads();
  unsigned total = start[NKEY - 1] + cnt[NKEY - 1];
  if ((unsigned)tid < total) {
    unsigned k = lkey[tid];
    size_t slot = (size_t)gbase[k] + (unsigned)tid - start[k];
    u64* d = sorted + slot * 3;
    const u64* s = (const u64*)&lrec[tid * 6];
    d[0] = s[0]; d[1] = s[1]; d[2] = s[2];
  }
}

// gather: stream sorted recs (material-contiguous), 4-corner interp from the
// fp16 table (3.84 MB per material -> per-XCD L2 resident), write out[idx].
__global__ __launch_bounds__(256) void gather_sorted_kernel(
    const u64* __restrict__ sorted, const u64* __restrict__ tbl,
    float* __restrict__ out, int N) {
  int n = blockIdx.x * blockDim.x + threadIdx.x;
  if (n >= N) return;
  const u64* rp = sorted + (size_t)n * 3;
  u64 r0 = __builtin_nontemporal_load(&rp[0]);
  u64 r1 = __builtin_nontemporal_load(&rp[1]);
  u64 r2 = __builtin_nontemporal_load(&rp[2]);
  float x0 = __uint_as_float((unsigned)(r0 & 0xFFFFFFFFu));
  float x1 = __uint_as_float((unsigned)(r0 >> 32));
  float x2 = __uint_as_float((unsigned)(r1 & 0xFFFFFFFFu));
  float iu = __uint_as_float((unsigned)(r1 >> 32));
  float jv = __uint_as_float((unsigned)(r2 & 0xFFFFFFFFu));
  unsigned meta = (unsigned)(r2 >> 32);

  float w[4]; int t[4];
  corner_setup(iu, jv, w, t);
  const u64* base = tbl + (size_t)(meta >> 30) * ((size_t)TEXELS * 3);

  float acc[12];
#pragma unroll
  for (int c = 0; c < 12; ++c) acc[c] = 0.0f;
#pragma unroll
  for (int c = 0; c < 4; ++c) {
    const u64* p = base + (size_t)t[c] * 3;
    u64 qa = p[0], qb = p[1], qc = p[2];
    float wc = w[c];
    float2 f;
    unsigned h;
    h = (unsigned)(qa & 0xFFFFFFFFu);  f = __half22float2(*(const __half2*)&h);
    acc[0] = fmaf(wc, f.x, acc[0]);  acc[1] = fmaf(wc, f.y, acc[1]);
    h = (unsigned)(qa >> 32);          f = __half22float2(*(const __half2*)&h);
    acc[2] = fmaf(wc, f.x, acc[2]);  acc[3] = fmaf(wc, f.y, acc[3]);
    h = (unsigned)(qb & 0xFFFFFFFFu);  f = __half22float2(*(const __half2*)&h);
    acc[4] = fmaf(wc, f.x, acc[4]);  acc[5] = fmaf(wc, f.y, acc[5]);
    h = (unsigned)(qb >> 32);          f = __half22float2(*(const __half2*)&h);
    acc[6] = fmaf(wc, f.x, acc[6]);  acc[7] = fmaf(wc, f.y, acc[7]);
    h = (unsigned)(qc & 0xFFFFFFFFu);  f = __half22float2(*(const __half2*)&h);
    acc[8] = fmaf(wc, f.x, acc[8]);  acc[9] = fmaf(wc, f.y, acc[9]);
    h = (unsigned)(qc >> 32);          f = __half22float2(*(const __half2*)&h);
    acc[10] = fmaf(wc, f.x, acc[10]); acc[11] = fmaf(wc, f.y, acc[11]);
  }

  unsigned idx = meta & 0x3FFFFFFFu;
  float o0 = fmaf(x0, acc[0], fmaf(x1, acc[3], fmaf(x2, acc[6], acc[9])));
  float o1 = fmaf(x0, acc[1], fmaf(x1, acc[4], fmaf(x2, acc[7], acc[10])));
  float o2 = fmaf(x0, acc[2], fmaf(x1, acc[5], fmaf(x2, acc[8], acc[11])));
  __builtin_nontemporal_store(o0, &out[3 * idx + 0]);
  __builtin_nontemporal_store(o1, &out[3 * idx + 1]);
  __builtin_nontemporal_store(o2, &out[3 * idx + 2]);
}

// ---------------- fallback kernels (low workspace) ----------------

__global__ __launch_bounds__(256) void repack_kernel(
    const float* __restrict__ mp, const float* __restrict__ bp,
    float* __restrict__ packed, int total_dwords) {
  int idx = blockIdx.x * blockDim.x + threadIdx.x;
  if (idx >= total_dwords) return;
  int t = idx >> 4;
  int k = idx & 15;
  float val = 0.0f;
  if (k < 9)       val = mp[t * 9 + k];
  else if (k < 12) val = bp[t * 3 + (k - 9)];
  packed[idx] = val;
}

__device__ __forceinline__ void finish_point(const float* acc, float x0, float x1,
                                             float x2, float* __restrict__ out,
                                             unsigned idx) {
  float o0 = fmaf(x0, acc[0], fmaf(x1, acc[3], fmaf(x2, acc[6], acc[9])));
  float o1 = fmaf(x0, acc[1], fmaf(x1, acc[4], fmaf(x2, acc[7], acc[10])));
  float o2 = fmaf(x0, acc[2], fmaf(x1, acc[5], fmaf(x2, acc[8], acc[11])));
  out[3 * idx + 0] = o0;
  out[3 * idx + 1] = o1;
  out[3 * idx + 2] = o2;
}

__global__ __launch_bounds__(256) void interp_packed_kernel(
    const float* __restrict__ x, const int* __restrict__ mat,
    const float* __restrict__ u, const float* __restrict__ v,
    const float4* __restrict__ packed, float* __restrict__ out, int N) {
  int n = blockIdx.x * blockDim.x + threadIdx.x;
  if (n >= N) return;
  float iu, jv;
  uv_to_coords(u[n], v[n], iu, jv);
  float w[4]; int t[4];
  corner_setup(iu, jv, w, t);
  const float4* base = packed + (size_t)mat[n] * ((size_t)TEXELS * 4);
  float acc[12];
#pragma unroll
  for (int c = 0; c < 12; ++c) acc[c] = 0.0f;
#pragma unroll
  for (int c = 0; c < 4; ++c) {
    const float4* p = base + (size_t)t[c] * 4;
    float4 q0 = p[0];
    float4 q1 = p[1];
    float4 q2 = p[2];
    float wc = w[c];
    acc[0]  = fmaf(wc, q0.x, acc[0]);
    acc[1]  = fmaf(wc, q0.y, acc[1]);
    acc[2]  = fmaf(wc, q0.z, acc[2]);
    acc[3]  = fmaf(wc, q0.w, acc[3]);
    acc[4]  = fmaf(wc, q1.x, acc[4]);
    acc[5]  = fmaf(wc, q1.y, acc[5]);
    acc[6]  = fmaf(wc, q1.z, acc[6]);
    acc[7]  = fmaf(wc, q1.w, acc[7]);
    acc[8]  = fmaf(wc, q2.x, acc[8]);
    acc[9]  = fmaf(wc, q2.y, acc[9]);
    acc[10] = fmaf(wc, q2.z, acc[10]);
    acc[11] = fmaf(wc, q2.w, acc[11]);
  }
  finish_point(acc, x[3 * n], x[3 * n + 1], x[3 * n + 2], out, (unsigned)n);
}

__global__ __launch_bounds__(256) void interp_direct_kernel(
    const float* __restrict__ x, const int* __restrict__ mat,
    const float* __restrict__ u, const float* __restrict__ v,
    const float* __restrict__ mp, const float* __restrict__ bp,
    float* __restrict__ out, int N) {
  int n = blockIdx.x * blockDim.x + threadIdx.x;
  if (n >= N) return;
  float iu, jv;
  uv_to_coords(u[n], v[n], iu, jv);
  float w[4]; int t[4];
  corner_setup(iu, jv, w, t);
  size_t mb = (size_t)mat[n] * TEXELS;
  float acc[12];
#pragma unroll
  for (int c = 0; c < 12; ++c) acc[c] = 0.0f;
#pragma unroll
  for (int c = 0; c < 4; ++c) {
    const float* pm = mp + (mb + t[c]) * 9;
    const float* pb = bp + (mb + t[c]) * 3;
    float wc = w[c];
#pragma unroll
    for (int k = 0; k < 9; ++k) acc[k] = fmaf(wc, pm[k], acc[k]);
#pragma unroll
    for (int k = 0; k < 3; ++k) acc[9 + k] = fmaf(wc, pb[k], acc[9 + k]);
  }
  finish_point(acc, x[3 * n], x[3 * n + 1], x[3 * n + 2], out, (unsigned)n);
}

// ---------------- launch ----------------

static inline size_t align_up(size_t v, size_t a) { return (v + a - 1) & ~(a - 1); }

extern "C" void kernel_launch(void* const* d_in, const int* in_sizes, int n_in,
                              void* d_out, int out_size, void* d_ws, size_t ws_size,
                              hipStream_t stream) {
  const float* x  = (const float*)d_in[0];
  const int*   m  = (const int*)d_in[1];
  const float* u  = (const float*)d_in[2];
  const float* v  = (const float*)d_in[3];
  const float* mp = (const float*)d_in[4];
  const float* bp = (const float*)d_in[5];
  float* out = (float*)d_out;

  int N = in_sizes[1];
  int M = in_sizes[4] / (TEXELS * 9);

  const int B = 256;
  int nblk = (N + B - 1) / B;

  size_t tbl16_bytes = (size_t)M * TEXELS * 24;       // fp16 records
  size_t ctl_bytes   = 256;                            // hist[4] + cursor[4]
  size_t sort_bytes  = (size_t)N * 24;                 // Rec stream
  size_t need_full = align_up(tbl16_bytes, 256) + ctl_bytes + sort_bytes;
  bool meta_ok = (M <= NKEY) && (N <= (1 << 30));

  if (meta_ok && ws_size >= need_full) {
    char* basep = (char*)d_ws;
    u64*      tbl    = (u64*)basep;
    unsigned* hist   = (unsigned*)(basep + align_up(tbl16_bytes, 256));
    unsigned* cursor = hist + NKEY;
    u64*      sorted = (u64*)((char*)hist + ctl_bytes);

    zero8_kernel<<<1, 64, 0, stream>>>(hist);
    int total_texels = M * TEXELS;
    repack_fp16_kernel<<<(total_texels + B - 1) / B, B, 0, stream>>>(
        mp, bp, tbl, total_texels);
    hist_kernel<<<nblk, B, 0, stream>>>(m, hist, N);
    scan4_kernel<<<1, 64, 0, stream>>>(hist, cursor);
    scatter_kernel<<<nblk, B, 0, stream>>>(x, m, u, v, cursor, sorted, N);
    gather_sorted_kernel<<<nblk, B, 0, stream>>>(sorted, tbl, out, N);
  } else if (ws_size >= (size_t)M * TEXELS * 16 * sizeof(float)) {
    int total_dwords = M * TEXELS * 16;
    repack_kernel<<<(total_dwords + B - 1) / B, B, 0, stream>>>(
        mp, bp, (float*)d_ws, total_dwords);
    interp_packed_kernel<<<nblk, B, 0, stream>>>(
        x, m, u, v, (const float4*)d_ws, out, N);
  } else {
    interp_direct_kernel<<<nblk, B, 0, stream>>>(x, m, u, v, mp, bp, out, N);
  }
}

// Round 5
// 367.549 us; speedup vs baseline: 2.1987x; 1.6573x over previous
//
#include <hip/hip_runtime.h>
#include <hip/hip_fp16.h>

#define U_DIM 400
#define V_DIM 400
#define TEXELS (U_DIM * V_DIM)
#define NKEY 4                 // materials
#define NREP 1024              // cursor replicas per key (kills atomic contention)

typedef unsigned long long u64;

__device__ __forceinline__ void uv_to_coords(float uu, float vv,
                                             float& iu, float& jv) {
  iu = uu * (float)U_DIM; if (iu >= (float)U_DIM) iu = (float)(U_DIM - 1);
  jv = vv * (float)V_DIM; if (jv >= (float)V_DIM) jv = (float)(V_DIM - 1);
}

__device__ __forceinline__ void corner_setup(float iu, float jv,
                                             float* w, int* t) {
  float i1f = floorf(iu), j1f = floorf(jv);
  int i1 = (int)i1f, j1 = (int)j1f;
  int i2 = i1 + 1; if (i2 == U_DIM) i2 = 0;
  int j2 = j1 + 1; if (j2 == V_DIM) j2 = 0;
  float ir = iu - i1f, jr = jv - j1f;
  w[0] = (1.0f - ir) * (1.0f - jr);
  w[1] = ir * (1.0f - jr);
  w[2] = (1.0f - ir) * jr;
  w[3] = ir * jr;
  t[0] = i1 * V_DIM + j1;
  t[1] = i2 * V_DIM + j1;
  t[2] = i1 * V_DIM + j2;
  t[3] = i2 * V_DIM + j2;
}

// ---------------- pipeline kernels ----------------

__global__ __launch_bounds__(256) void zero_kernel(unsigned* __restrict__ p, int n) {
  int i = blockIdx.x * blockDim.x + threadIdx.x;
  if (i < n) p[i] = 0u;
}

// fp16 split repack: tbl0 = 16B/texel (W[0..7]), tbl1 = 8B/texel (W[8],b0,b1,b2)
__global__ __launch_bounds__(256) void repack_split_kernel(
    const float* __restrict__ mp, const float* __restrict__ bp,
    u64* __restrict__ tbl0, u64* __restrict__ tbl1, int total_texels) {
  int t = blockIdx.x * blockDim.x + threadIdx.x;
  if (t >= total_texels) return;
  const float* pw = mp + (size_t)t * 9;
  const float* pb = bp + (size_t)t * 3;
  union { __half h[12]; u64 q[3]; } u;
#pragma unroll
  for (int k = 0; k < 8; ++k) u.h[k] = __float2half(pw[k]);
  u.h[8]  = __float2half(pw[8]);
  u.h[9]  = __float2half(pb[0]);
  u.h[10] = __float2half(pb[1]);
  u.h[11] = __float2half(pb[2]);
  tbl0[(size_t)t * 2 + 0] = u.q[0];
  tbl0[(size_t)t * 2 + 1] = u.q[1];
  tbl1[t] = u.q[2];
}

// wave-level ballot histogram -> 4 atomics per wave on replicated counters
__global__ __launch_bounds__(256) void hist_kernel(
    const int* __restrict__ m, unsigned* __restrict__ hist, int N) {
  int gid = blockIdx.x * blockDim.x + threadIdx.x;
  int lane = threadIdx.x & 63;
  unsigned rep = ((unsigned)(gid >> 6)) & (NREP - 1);
  int idx4 = gid * 4;
  unsigned cnt[NKEY] = {0u, 0u, 0u, 0u};
#pragma unroll
  for (int r = 0; r < 4; ++r) {
    int nn = idx4 + r;
    int key = (nn < N) ? m[nn] : -1;
#pragma unroll
    for (int k = 0; k < NKEY; ++k) {
      u64 mask = __ballot(key == k);
      cnt[k] += (unsigned)__popcll(mask);
    }
  }
  if (lane == 0) {
#pragma unroll
    for (int k = 0; k < NKEY; ++k)
      if (cnt[k]) atomicAdd(&hist[k * NREP + rep], cnt[k]);
  }
}

#define SCAN_THREADS 1024
// single-workgroup exclusive scan over NKEY*NREP = 4096 entries (key-major)
__global__ __launch_bounds__(SCAN_THREADS) void scan_kernel(
    const unsigned* __restrict__ hist, unsigned* __restrict__ cursor, int nb) {
  __shared__ unsigned buf[2][SCAN_THREADS];
  __shared__ unsigned carry_s;
  if (threadIdx.x == 0) carry_s = 0u;
  __syncthreads();
  for (int base = 0; base < nb; base += SCAN_THREADS) {
    int i = base + threadIdx.x;
    unsigned vv = (i < nb) ? hist[i] : 0u;
    int src = 0;
    buf[0][threadIdx.x] = vv;
    __syncthreads();
    for (int off = 1; off < SCAN_THREADS; off <<= 1) {
      unsigned t = buf[src][threadIdx.x];
      if ((int)threadIdx.x >= off) t += buf[src][threadIdx.x - off];
      buf[1 - src][threadIdx.x] = t;
      src = 1 - src;
      __syncthreads();
    }
    unsigned incl = buf[src][threadIdx.x];
    unsigned excl = incl - vv + carry_s;
    if (i < nb) cursor[i] = excl;
    __syncthreads();
    if (threadIdx.x == SCAN_THREADS - 1) carry_s += incl;
    __syncthreads();
  }
}

// scatter: LDS-group 256 points by material, claim contiguous runs from
// replicated cursors, write 24B recs coalesced; also inv[n]=slot (coalesced).
__global__ __launch_bounds__(256) void scatter_kernel(
    const float* __restrict__ x, const int* __restrict__ m,
    const float* __restrict__ u, const float* __restrict__ v,
    unsigned* __restrict__ cursor, u64* __restrict__ sorted,
    unsigned* __restrict__ inv, int N) {
  __shared__ unsigned cnt[NKEY], start[NKEY], gbase[NKEY];
  __shared__ unsigned lkey[256];
  __shared__ float lrec[256 * 6];

  int tid = threadIdx.x;
  int n = blockIdx.x * blockDim.x + tid;
  bool valid = (n < N);
  unsigned rep = blockIdx.x & (NREP - 1);

  unsigned key = 0;
  float rec[6];
  if (valid) {
    int mm = __builtin_nontemporal_load(&m[n]);
    float uu = __builtin_nontemporal_load(&u[n]);
    float vv = __builtin_nontemporal_load(&v[n]);
    float iu, jv;
    uv_to_coords(uu, vv, iu, jv);
    rec[0] = __builtin_nontemporal_load(&x[3 * n + 0]);
    rec[1] = __builtin_nontemporal_load(&x[3 * n + 1]);
    rec[2] = __builtin_nontemporal_load(&x[3 * n + 2]);
    rec[3] = iu;
    rec[4] = jv;
    rec[5] = __uint_as_float((unsigned)mm);   // material only; idx via inv[]
    key = (unsigned)mm;
  }

  if (tid < NKEY) cnt[tid] = 0u;
  __syncthreads();
  unsigned rank = valid ? atomicAdd(&cnt[key], 1u) : 0u;
  __syncthreads();
  if (tid < NKEY) gbase[tid] = atomicAdd(&cursor[tid * NREP + rep], cnt[tid]);
  if (tid == 0) {
    unsigned s = 0;
#pragma unroll
    for (int k = 0; k < NKEY; ++k) { start[k] = s; s += cnt[k]; }
  }
  __syncthreads();
  if (valid) {
    unsigned lpos = start[key] + rank;
    lkey[lpos] = key;
#pragma unroll
    for (int k = 0; k < 6; ++k) lrec[lpos * 6 + k] = rec[k];
    inv[n] = gbase[key] + rank;               // coalesced in n
  }
  __syncthreads();
  unsigned total = start[NKEY - 1] + cnt[NKEY - 1];
  if ((unsigned)tid < total) {
    unsigned k = lkey[tid];
    size_t slot = (size_t)gbase[k] + (unsigned)tid - start[k];
    u64* d = sorted + slot * 3;
    const u64* s = (const u64*)&lrec[tid * 6];
    d[0] = s[0]; d[1] = s[1]; d[2] = s[2];
  }
}

// gather: 4 corners x (dwordx4 + dwordx2) fp16 loads; result written IN PLACE
// over the first 12B of the record this thread just consumed (race-free).
__global__ __launch_bounds__(256) void gather_inplace_kernel(
    u64* __restrict__ sorted, const u64* __restrict__ tbl0,
    const u64* __restrict__ tbl1, int N) {
  int n = blockIdx.x * blockDim.x + threadIdx.x;
  if (n >= N) return;
  u64* rp = sorted + (size_t)n * 3;
  u64 r0 = rp[0];
  u64 r1 = rp[1];
  u64 r2 = rp[2];
  float x0 = __uint_as_float((unsigned)(r0 & 0xFFFFFFFFu));
  float x1 = __uint_as_float((unsigned)(r0 >> 32));
  float x2 = __uint_as_float((unsigned)(r1 & 0xFFFFFFFFu));
  float iu = __uint_as_float((unsigned)(r1 >> 32));
  float jv = __uint_as_float((unsigned)(r2 & 0xFFFFFFFFu));
  unsigned mm = (unsigned)(r2 >> 32);

  float w[4]; int t[4];
  corner_setup(iu, jv, w, t);
  const u64* b0 = tbl0 + (size_t)mm * ((size_t)TEXELS * 2);
  const u64* b1 = tbl1 + (size_t)mm * (size_t)TEXELS;

  float acc[12];
#pragma unroll
  for (int c = 0; c < 12; ++c) acc[c] = 0.0f;
#pragma unroll
  for (int c = 0; c < 4; ++c) {
    const u64* p0 = b0 + (size_t)t[c] * 2;
    u64 qa = p0[0], qb = p0[1];
    u64 qc = b1[t[c]];
    float wc = w[c];
    float2 f;
    unsigned h;
    h = (unsigned)(qa & 0xFFFFFFFFu);  f = __half22float2(*(const __half2*)&h);
    acc[0] = fmaf(wc, f.x, acc[0]);  acc[1] = fmaf(wc, f.y, acc[1]);
    h = (unsigned)(qa >> 32);          f = __half22float2(*(const __half2*)&h);
    acc[2] = fmaf(wc, f.x, acc[2]);  acc[3] = fmaf(wc, f.y, acc[3]);
    h = (unsigned)(qb & 0xFFFFFFFFu);  f = __half22float2(*(const __half2*)&h);
    acc[4] = fmaf(wc, f.x, acc[4]);  acc[5] = fmaf(wc, f.y, acc[5]);
    h = (unsigned)(qb >> 32);          f = __half22float2(*(const __half2*)&h);
    acc[6] = fmaf(wc, f.x, acc[6]);  acc[7] = fmaf(wc, f.y, acc[7]);
    h = (unsigned)(qc & 0xFFFFFFFFu);  f = __half22float2(*(const __half2*)&h);
    acc[8] = fmaf(wc, f.x, acc[8]);  acc[9] = fmaf(wc, f.y, acc[9]);
    h = (unsigned)(qc >> 32);          f = __half22float2(*(const __half2*)&h);
    acc[10] = fmaf(wc, f.x, acc[10]); acc[11] = fmaf(wc, f.y, acc[11]);
  }

  float o0 = fmaf(x0, acc[0], fmaf(x1, acc[3], fmaf(x2, acc[6], acc[9])));
  float o1 = fmaf(x0, acc[1], fmaf(x1, acc[4], fmaf(x2, acc[7], acc[10])));
  float o2 = fmaf(x0, acc[2], fmaf(x1, acc[5], fmaf(x2, acc[8], acc[11])));
  u64 lo = (u64)__float_as_uint(o0) | ((u64)__float_as_uint(o1) << 32);
  rp[0] = lo;
  ((unsigned*)rp)[2] = __float_as_uint(o2);
}

// unsort: out[3n] = result stored at sorted[inv[n]] (monotonic runs -> coalesced)
__global__ __launch_bounds__(256) void unsort_kernel(
    const unsigned* __restrict__ inv, const u64* __restrict__ sorted,
    float* __restrict__ out, int N) {
  int n = blockIdx.x * blockDim.x + threadIdx.x;
  if (n >= N) return;
  unsigned slot = __builtin_nontemporal_load(&inv[n]);
  const u64* p = sorted + (size_t)slot * 3;
  u64 lo = p[0];
  unsigned o2 = ((const unsigned*)p)[2];
  __builtin_nontemporal_store(__uint_as_float((unsigned)(lo & 0xFFFFFFFFu)), &out[3 * n + 0]);
  __builtin_nontemporal_store(__uint_as_float((unsigned)(lo >> 32)), &out[3 * n + 1]);
  __builtin_nontemporal_store(__uint_as_float(o2), &out[3 * n + 2]);
}

// gather variant writing out[idx] directly (tier-b: no inv array)
__global__ __launch_bounds__(256) void gather_out_kernel(
    const u64* __restrict__ sorted, const u64* __restrict__ tbl0,
    const u64* __restrict__ tbl1, float* __restrict__ out, int N) {
  int n = blockIdx.x * blockDim.x + threadIdx.x;
  if (n >= N) return;
  const u64* rp = sorted + (size_t)n * 3;
  u64 r0 = __builtin_nontemporal_load(&rp[0]);
  u64 r1 = __builtin_nontemporal_load(&rp[1]);
  u64 r2 = __builtin_nontemporal_load(&rp[2]);
  float x0 = __uint_as_float((unsigned)(r0 & 0xFFFFFFFFu));
  float x1 = __uint_as_float((unsigned)(r0 >> 32));
  float x2 = __uint_as_float((unsigned)(r1 & 0xFFFFFFFFu));
  float iu = __uint_as_float((unsigned)(r1 >> 32));
  float jv = __uint_as_float((unsigned)(r2 & 0xFFFFFFFFu));
  unsigned meta = (unsigned)(r2 >> 32);

  float w[4]; int t[4];
  corner_setup(iu, jv, w, t);
  const u64* b0 = tbl0 + (size_t)(meta >> 30) * ((size_t)TEXELS * 2);
  const u64* b1 = tbl1 + (size_t)(meta >> 30) * (size_t)TEXELS;

  float acc[12];
#pragma unroll
  for (int c = 0; c < 12; ++c) acc[c] = 0.0f;
#pragma unroll
  for (int c = 0; c < 4; ++c) {
    const u64* p0 = b0 + (size_t)t[c] * 2;
    u64 qa = p0[0], qb = p0[1];
    u64 qc = b1[t[c]];
    float wc = w[c];
    float2 f;
    unsigned h;
    h = (unsigned)(qa & 0xFFFFFFFFu);  f = __half22float2(*(const __half2*)&h);
    acc[0] = fmaf(wc, f.x, acc[0]);  acc[1] = fmaf(wc, f.y, acc[1]);
    h = (unsigned)(qa >> 32);          f = __half22float2(*(const __half2*)&h);
    acc[2] = fmaf(wc, f.x, acc[2]);  acc[3] = fmaf(wc, f.y, acc[3]);
    h = (unsigned)(qb & 0xFFFFFFFFu);  f = __half22float2(*(const __half2*)&h);
    acc[4] = fmaf(wc, f.x, acc[4]);  acc[5] = fmaf(wc, f.y, acc[5]);
    h = (unsigned)(qb >> 32);          f = __half22float2(*(const __half2*)&h);
    acc[6] = fmaf(wc, f.x, acc[6]);  acc[7] = fmaf(wc, f.y, acc[7]);
    h = (unsigned)(qc & 0xFFFFFFFFu);  f = __half22float2(*(const __half2*)&h);
    acc[8] = fmaf(wc, f.x, acc[8]);  acc[9] = fmaf(wc, f.y, acc[9]);
    h = (unsigned)(qc >> 32);          f = __half22float2(*(const __half2*)&h);
    acc[10] = fmaf(wc, f.x, acc[10]); acc[11] = fmaf(wc, f.y, acc[11]);
  }

  unsigned idx = meta & 0x3FFFFFFFu;
  float o0 = fmaf(x0, acc[0], fmaf(x1, acc[3], fmaf(x2, acc[6], acc[9])));
  float o1 = fmaf(x0, acc[1], fmaf(x1, acc[4], fmaf(x2, acc[7], acc[10])));
  float o2 = fmaf(x0, acc[2], fmaf(x1, acc[5], fmaf(x2, acc[8], acc[11])));
  out[3 * idx + 0] = o0;
  out[3 * idx + 1] = o1;
  out[3 * idx + 2] = o2;
}

// tier-b scatter (meta carries idx|m<<30, no inv)
__global__ __launch_bounds__(256) void scatter_meta_kernel(
    const float* __restrict__ x, const int* __restrict__ m,
    const float* __restrict__ u, const float* __restrict__ v,
    unsigned* __restrict__ cursor, u64* __restrict__ sorted, int N) {
  __shared__ unsigned cnt[NKEY], start[NKEY], gbase[NKEY];
  __shared__ unsigned lkey[256];
  __shared__ float lrec[256 * 6];

  int tid = threadIdx.x;
  int n = blockIdx.x * blockDim.x + tid;
  bool valid = (n < N);
  unsigned rep = blockIdx.x & (NREP - 1);

  unsigned key = 0;
  float rec[6];
  if (valid) {
    int mm = __builtin_nontemporal_load(&m[n]);
    float uu = __builtin_nontemporal_load(&u[n]);
    float vv = __builtin_nontemporal_load(&v[n]);
    float iu, jv;
    uv_to_coords(uu, vv, iu, jv);
    rec[0] = __builtin_nontemporal_load(&x[3 * n + 0]);
    rec[1] = __builtin_nontemporal_load(&x[3 * n + 1]);
    rec[2] = __builtin_nontemporal_load(&x[3 * n + 2]);
    rec[3] = iu;
    rec[4] = jv;
    rec[5] = __uint_as_float((unsigned)n | ((unsigned)mm << 30));
    key = (unsigned)mm;
  }

  if (tid < NKEY) cnt[tid] = 0u;
  __syncthreads();
  unsigned rank = valid ? atomicAdd(&cnt[key], 1u) : 0u;
  __syncthreads();
  if (tid < NKEY) gbase[tid] = atomicAdd(&cursor[tid * NREP + rep], cnt[tid]);
  if (tid == 0) {
    unsigned s = 0;
#pragma unroll
    for (int k = 0; k < NKEY; ++k) { start[k] = s; s += cnt[k]; }
  }
  __syncthreads();
  if (valid) {
    unsigned lpos = start[key] + rank;
    lkey[lpos] = key;
#pragma unroll
    for (int k = 0; k < 6; ++k) lrec[lpos * 6 + k] = rec[k];
  }
  __syncthreads();
  unsigned total = start[NKEY - 1] + cnt[NKEY - 1];
  if ((unsigned)tid < total) {
    unsigned k = lkey[tid];
    size_t slot = (size_t)gbase[k] + (unsigned)tid - start[k];
    u64* d = sorted + slot * 3;
    const u64* s = (const u64*)&lrec[tid * 6];
    d[0] = s[0]; d[1] = s[1]; d[2] = s[2];
  }
}

// ---------------- low-workspace fallback ----------------

__global__ __launch_bounds__(256) void interp_direct_kernel(
    const float* __restrict__ x, const int* __restrict__ mat,
    const float* __restrict__ u, const float* __restrict__ v,
    const float* __restrict__ mp, const float* __restrict__ bp,
    float* __restrict__ out, int N) {
  int n = blockIdx.x * blockDim.x + threadIdx.x;
  if (n >= N) return;
  float iu, jv;
  uv_to_coords(u[n], v[n], iu, jv);
  float w[4]; int t[4];
  corner_setup(iu, jv, w, t);
  size_t mb = (size_t)mat[n] * TEXELS;
  float acc[12];
#pragma unroll
  for (int c = 0; c < 12; ++c) acc[c] = 0.0f;
#pragma unroll
  for (int c = 0; c < 4; ++c) {
    const float* pm = mp + (mb + t[c]) * 9;
    const float* pb = bp + (mb + t[c]) * 3;
    float wc = w[c];
#pragma unroll
    for (int k = 0; k < 9; ++k) acc[k] = fmaf(wc, pm[k], acc[k]);
#pragma unroll
    for (int k = 0; k < 3; ++k) acc[9 + k] = fmaf(wc, pb[k], acc[9 + k]);
  }
  float x0 = x[3 * n], x1 = x[3 * n + 1], x2 = x[3 * n + 2];
  float o0 = fmaf(x0, acc[0], fmaf(x1, acc[3], fmaf(x2, acc[6], acc[9])));
  float o1 = fmaf(x0, acc[1], fmaf(x1, acc[4], fmaf(x2, acc[7], acc[10])));
  float o2 = fmaf(x0, acc[2], fmaf(x1, acc[5], fmaf(x2, acc[8], acc[11])));
  out[3 * n + 0] = o0;
  out[3 * n + 1] = o1;
  out[3 * n + 2] = o2;
}

// ---------------- launch ----------------

static inline size_t align_up(size_t v, size_t a) { return (v + a - 1) & ~(a - 1); }

extern "C" void kernel_launch(void* const* d_in, const int* in_sizes, int n_in,
                              void* d_out, int out_size, void* d_ws, size_t ws_size,
                              hipStream_t stream) {
  const float* x  = (const float*)d_in[0];
  const int*   m  = (const int*)d_in[1];
  const float* u  = (const float*)d_in[2];
  const float* v  = (const float*)d_in[3];
  const float* mp = (const float*)d_in[4];
  const float* bp = (const float*)d_in[5];
  float* out = (float*)d_out;

  int N = in_sizes[1];
  int M = in_sizes[4] / (TEXELS * 9);

  const int B = 256;
  int nblk = (N + B - 1) / B;
  int nctl = NKEY * NREP;

  size_t tbl0_bytes = (size_t)M * TEXELS * 16;
  size_t tbl1_bytes = (size_t)M * TEXELS * 8;
  size_t ctl_bytes  = (size_t)nctl * sizeof(unsigned);   // x2 (hist + cursor)
  size_t sort_bytes = (size_t)N * 24;
  size_t inv_bytes  = (size_t)N * sizeof(unsigned);

  size_t off_tbl0  = 0;
  size_t off_tbl1  = align_up(off_tbl0 + tbl0_bytes, 256);
  size_t off_hist  = align_up(off_tbl1 + tbl1_bytes, 256);
  size_t off_curs  = align_up(off_hist + ctl_bytes, 256);
  size_t off_sort  = align_up(off_curs + ctl_bytes, 256);
  size_t off_inv   = align_up(off_sort + sort_bytes, 256);
  size_t need_a    = off_inv + inv_bytes;
  size_t need_b    = off_inv;   // everything except inv

  bool meta_ok = (M <= NKEY) && (N <= (1 << 30));
  char* basep = (char*)d_ws;

  if (meta_ok && ws_size >= need_a) {
    u64*      tbl0   = (u64*)(basep + off_tbl0);
    u64*      tbl1   = (u64*)(basep + off_tbl1);
    unsigned* hist   = (unsigned*)(basep + off_hist);
    unsigned* cursor = (unsigned*)(basep + off_curs);
    u64*      sorted = (u64*)(basep + off_sort);
    unsigned* inv    = (unsigned*)(basep + off_inv);

    zero_kernel<<<(nctl + B - 1) / B, B, 0, stream>>>(hist, nctl);
    int total_texels = M * TEXELS;
    repack_split_kernel<<<(total_texels + B - 1) / B, B, 0, stream>>>(
        mp, bp, tbl0, tbl1, total_texels);
    int nblk4 = (N + B * 4 - 1) / (B * 4);
    hist_kernel<<<nblk4, B, 0, stream>>>(m, hist, N);
    scan_kernel<<<1, SCAN_THREADS, 0, stream>>>(hist, cursor, nctl);
    scatter_kernel<<<nblk, B, 0, stream>>>(x, m, u, v, cursor, sorted, inv, N);
    gather_inplace_kernel<<<nblk, B, 0, stream>>>(sorted, tbl0, tbl1, N);
    unsort_kernel<<<nblk, B, 0, stream>>>(inv, sorted, out, N);
  } else if (meta_ok && ws_size >= need_b) {
    u64*      tbl0   = (u64*)(basep + off_tbl0);
    u64*      tbl1   = (u64*)(basep + off_tbl1);
    unsigned* hist   = (unsigned*)(basep + off_hist);
    unsigned* cursor = (unsigned*)(basep + off_curs);
    u64*      sorted = (u64*)(basep + off_sort);

    zero_kernel<<<(nctl + B - 1) / B, B, 0, stream>>>(hist, nctl);
    int total_texels = M * TEXELS;
    repack_split_kernel<<<(total_texels + B - 1) / B, B, 0, stream>>>(
        mp, bp, tbl0, tbl1, total_texels);
    int nblk4 = (N + B * 4 - 1) / (B * 4);
    hist_kernel<<<nblk4, B, 0, stream>>>(m, hist, N);
    scan_kernel<<<1, SCAN_THREADS, 0, stream>>>(hist, cursor, nctl);
    scatter_meta_kernel<<<nblk, B, 0, stream>>>(x, m, u, v, cursor, sorted, N);
    gather_out_kernel<<<nblk, B, 0, stream>>>(sorted, tbl0, tbl1, out, N);
  } else {
    interp_direct_kernel<<<nblk, B, 0, stream>>>(x, m, u, v, mp, bp, out, N);
  }
}